// Round 5
// baseline (447.217 us; speedup 1.0000x reference)
//
#include <hip/hip_runtime.h>

// MRR on MI355X. N_TOT = 8192 + 8192*4000 = 32,776,192 (divisible by 4).
// argsort(index) of a permutation is its inverse: element j is pos slot
// index[j] if index[j] < 8192, else neg of row (index[j]-8192)/4000.
//
// Budget (R1-R4 evidence): ~226 us of dur_us is harness restore/poison fills
// inside the timed window; kernel share ~63 us vs ~50 us floor
// (scatter: 131 MB idx from HBM; count: 131 MB pv from HBM + idx re-read
// from L3 — R3 FETCH=194 MB < 393 MB logical confirms L3 absorption).
// R5: fuse finalize into count via last-block ticket; unroll x4 for MLP.
//
// ws layout: [0,32KB) pos floats; [32KB,48KB) u64 cnt[2048] (4x16-bit rows
// per u64; per-row totals <= 4000 so fields never carry); then u64 ticket.

constexpr int N_POS = 8192;
constexpr int N_NEG = 4000;
constexpr int NSLOT = N_POS / 4;
constexpr int CNT_BLOCKS = 512;

typedef int   vint4   __attribute__((ext_vector_type(4)));
typedef float vfloat4 __attribute__((ext_vector_type(4)));
typedef unsigned int u32;
typedef unsigned long long u64;

// Pass 1: zero cnt+ticket + scatter the 8192 pos values. idx read #1
// (131 MB, plain loads so lines land in L3 for pass 2's re-read).
__global__ __launch_bounds__(256) void scatter_pos_kernel(
    const vint4* __restrict__ idx4, const float* __restrict__ pv,
    float* __restrict__ pos, u64* __restrict__ cnt, int nvec) {
  const int gtid = blockIdx.x * 256 + threadIdx.x;
  if (gtid <= NSLOT) cnt[gtid] = 0ull;   // slots 0..2047 + ticket at 2048
  const int stride = gridDim.x * 256;
  int j = gtid;
#define SC_ELEM(V, JJ)                                   \
  if ((V).x < N_POS) pos[(V).x] = pv[4 * (JJ) + 0];      \
  if ((V).y < N_POS) pos[(V).y] = pv[4 * (JJ) + 1];      \
  if ((V).z < N_POS) pos[(V).z] = pv[4 * (JJ) + 2];      \
  if ((V).w < N_POS) pos[(V).w] = pv[4 * (JJ) + 3];
  for (; j + 3 * stride < nvec; j += 4 * stride) {
    vint4 a = idx4[j];
    vint4 b = idx4[j + stride];
    vint4 c = idx4[j + 2 * stride];
    vint4 d = idx4[j + 3 * stride];
    SC_ELEM(a, j)
    SC_ELEM(b, j + stride)
    SC_ELEM(c, j + 2 * stride)
    SC_ELEM(d, j + 3 * stride)
  }
  for (; j < nvec; j += stride) {
    vint4 a = idx4[j];
    SC_ELEM(a, j)
  }
#undef SC_ELEM
}

// Pass 2: stream idx (#2, L3-resident) + pv (NT, single use). LDS pos stage
// + unpacked u32 LDS counters; flush as packed u64 global atomics; the LAST
// block to finish (ticket) computes sample_mrr + mean (fused finalize).
__global__ __launch_bounds__(1024) void count_kernel(
    const vint4* __restrict__ idx4, const vfloat4* __restrict__ pv4,
    const float* __restrict__ pos, u64* __restrict__ cnt,
    float* __restrict__ out, int nvec) {
  __shared__ float pos_lds[N_POS];   // 32 KB
  __shared__ u32   lcnt[N_POS];      // 32 KB -> 64 KB total: 2 blk/CU,
                                     // 1024 thr = 32 waves/CU (full occ)
  __shared__ float wsum[16];
  __shared__ int is_last;
  for (int i = threadIdx.x; i < N_POS; i += 1024) {
    pos_lds[i] = pos[i];
    lcnt[i] = 0u;
  }
  __syncthreads();

  const int stride = gridDim.x * 1024;
  int j = blockIdx.x * 1024 + threadIdx.x;
#define CT_ELEM(IV, XV)                                              \
  if ((IV) >= N_POS) {                                               \
    unsigned r = (unsigned)((IV) - N_POS) / (unsigned)N_NEG;         \
    if ((XV) > pos_lds[r]) atomicAdd(&lcnt[r], 1u);                  \
  }
#define CT_VEC(V, X)                                                 \
  CT_ELEM((V).x, (X).x) CT_ELEM((V).y, (X).y)                        \
  CT_ELEM((V).z, (X).z) CT_ELEM((V).w, (X).w)
  for (; j + 3 * stride < nvec; j += 4 * stride) {
    vint4 va = idx4[j];
    vint4 vb = idx4[j + stride];
    vint4 vc = idx4[j + 2 * stride];
    vint4 vd = idx4[j + 3 * stride];
    vfloat4 xa = __builtin_nontemporal_load(&pv4[j]);
    vfloat4 xb = __builtin_nontemporal_load(&pv4[j + stride]);
    vfloat4 xc = __builtin_nontemporal_load(&pv4[j + 2 * stride]);
    vfloat4 xd = __builtin_nontemporal_load(&pv4[j + 3 * stride]);
    CT_VEC(va, xa)
    CT_VEC(vb, xb)
    CT_VEC(vc, xc)
    CT_VEC(vd, xd)
  }
  for (; j < nvec; j += stride) {
    vint4 va = idx4[j];
    vfloat4 xa = __builtin_nontemporal_load(&pv4[j]);
    CT_VEC(va, xa)
  }
#undef CT_VEC
#undef CT_ELEM
  __syncthreads();

  for (int s = threadIdx.x; s < NSLOT; s += 1024) {
    u32 c0 = lcnt[4 * s + 0], c1 = lcnt[4 * s + 1];
    u32 c2 = lcnt[4 * s + 2], c3 = lcnt[4 * s + 3];
    u64 p = (u64)c0 | ((u64)c1 << 16) | ((u64)c2 << 32) | ((u64)c3 << 48);
    if (p) atomicAdd(&cnt[s], p);
  }

  // ---- last-block-done finalize ----
  __threadfence();   // release: make this block's cnt atomics visible
  if (threadIdx.x == 0) {
    u64 prev = atomicAdd(&cnt[NSLOT], 1ull);   // ticket
    is_last = (prev == (u64)(gridDim.x - 1));
  }
  __syncthreads();
  if (!is_last) return;
  __threadfence();   // acquire

  float lsum = 0.f;
  for (int s = threadIdx.x; s < NSLOT; s += 1024) {
    u64 p = __hip_atomic_load(&cnt[s], __ATOMIC_RELAXED,
                              __HIP_MEMORY_SCOPE_AGENT);
    float m0 = 1.0f / (float)(1u + (u32)(p & 0xFFFFu));
    float m1 = 1.0f / (float)(1u + (u32)((p >> 16) & 0xFFFFu));
    float m2 = 1.0f / (float)(1u + (u32)((p >> 32) & 0xFFFFu));
    float m3 = 1.0f / (float)(1u + (u32)((p >> 48) & 0xFFFFu));
    vfloat4 m = {m0, m1, m2, m3};
    *(vfloat4*)&out[1 + 4 * s] = m;
    lsum += m0 + m1 + m2 + m3;
  }
#pragma unroll
  for (int off = 32; off > 0; off >>= 1) lsum += __shfl_down(lsum, off, 64);
  if ((threadIdx.x & 63) == 0) wsum[threadIdx.x >> 6] = lsum;
  __syncthreads();
  if (threadIdx.x == 0) {
    float tot = 0.f;
#pragma unroll
    for (int w = 0; w < 16; ++w) tot += wsum[w];
    out[0] = tot / (float)N_POS;
  }
}

extern "C" void kernel_launch(void* const* d_in, const int* in_sizes, int n_in,
                              void* d_out, int out_size, void* d_ws, size_t ws_size,
                              hipStream_t stream) {
  const float* pv = (const float*)d_in[0];
  const int* idx = (const int*)d_in[1];
  float* out = (float*)d_out;
  float* pos = (float*)d_ws;
  u64* cnt = (u64*)((char*)d_ws + 32 * 1024);   // 2048 slots + ticket
  int nvec = in_sizes[0] / 4;   // 8,194,048

  scatter_pos_kernel<<<2048, 256, 0, stream>>>((const vint4*)idx, pv, pos,
                                               cnt, nvec);
  count_kernel<<<CNT_BLOCKS, 1024, 0, stream>>>((const vint4*)idx,
                                                (const vfloat4*)pv, pos, cnt,
                                                out, nvec);
}

// Round 6
// 286.238 us; speedup vs baseline: 1.5624x; 1.5624x over previous
//
#include <hip/hip_runtime.h>

// MRR on MI355X. N_TOT = 8192 + 8192*4000 = 32,776,192 (divisible by 4).
// argsort(index) of a permutation is its inverse: element j is pos slot
// index[j] if index[j] < 8192, else neg of row (index[j]-8192)/4000.
//
// Evidence trail: ~226 us of every dur_us is harness restore/poison fills
// (three ~76 us 512 MB fillBuffer dispatches). Kernel budget ~63 us (R4).
// R5 lesson: per-thread __threadfence() => per-wave buffer_wbl2+buffer_inv
// (agent fences on non-coherent per-XCD L2s) — count went 3x slower.
// R6: fused finalize kept, but FENCE-FREE: device-scope atomics bypass L2,
// and __syncthreads drains vmcnt(0) per wave, so a post-barrier relaxed
// ticket is already ordered. Loops restored to R4's proven x2 unroll.
//
// ws layout: [0,32KB) pos floats; [32KB..) u64 cnt[2048] (4x16-bit rows per
// u64; per-row totals <= 4000 so fields never carry) + u64 ticket at [2048].

constexpr int N_POS = 8192;
constexpr int N_NEG = 4000;
constexpr int NSLOT = N_POS / 4;
constexpr int CNT_BLOCKS = 512;

typedef int   vint4   __attribute__((ext_vector_type(4)));
typedef float vfloat4 __attribute__((ext_vector_type(4)));
typedef unsigned int u32;
typedef unsigned long long u64;

// Pass 1: zero cnt+ticket + scatter the 8192 pos values. idx read #1
// (131 MB, plain loads so lines land in L3 for pass 2's re-read).
__global__ __launch_bounds__(256) void scatter_pos_kernel(
    const vint4* __restrict__ idx4, const float* __restrict__ pv,
    float* __restrict__ pos, u64* __restrict__ cnt, int nvec) {
  const int gtid = blockIdx.x * 256 + threadIdx.x;
  if (gtid <= NSLOT) cnt[gtid] = 0ull;   // slots 0..2047 + ticket at 2048
  const int stride = gridDim.x * 256;
  int j = gtid;
#define SC_ELEM(V, JJ)                                   \
  if ((V).x < N_POS) pos[(V).x] = pv[4 * (JJ) + 0];      \
  if ((V).y < N_POS) pos[(V).y] = pv[4 * (JJ) + 1];      \
  if ((V).z < N_POS) pos[(V).z] = pv[4 * (JJ) + 2];      \
  if ((V).w < N_POS) pos[(V).w] = pv[4 * (JJ) + 3];
  for (; j + stride < nvec; j += 2 * stride) {
    vint4 a = idx4[j];
    vint4 b = idx4[j + stride];
    SC_ELEM(a, j)
    SC_ELEM(b, j + stride)
  }
  for (; j < nvec; j += stride) {
    vint4 a = idx4[j];
    SC_ELEM(a, j)
  }
#undef SC_ELEM
}

// Pass 2: stream idx (#2, L3-resident) + pv (NT, single use). LDS pos stage
// + unpacked u32 LDS counters; flush as packed u64 device-scope atomics;
// last block (relaxed ticket, post-barrier so all atomics drained) computes
// sample_mrr + mean. NO agent fences anywhere.
__global__ __launch_bounds__(1024) void count_kernel(
    const vint4* __restrict__ idx4, const vfloat4* __restrict__ pv4,
    const float* __restrict__ pos, u64* __restrict__ cnt,
    float* __restrict__ out, int nvec) {
  __shared__ float pos_lds[N_POS];   // 32 KB
  __shared__ u32   lcnt[N_POS];      // 32 KB -> 64 KB total: 2 blk/CU,
                                     // 1024 thr = 32 waves/CU (full occ)
  __shared__ float wsum[16];
  __shared__ int is_last;
  for (int i = threadIdx.x; i < N_POS; i += 1024) {
    pos_lds[i] = pos[i];
    lcnt[i] = 0u;
  }
  __syncthreads();

  const int stride = gridDim.x * 1024;
  int j = blockIdx.x * 1024 + threadIdx.x;
#define CT_ELEM(IV, XV)                                              \
  if ((IV) >= N_POS) {                                               \
    unsigned r = (unsigned)((IV) - N_POS) / (unsigned)N_NEG;         \
    if ((XV) > pos_lds[r]) atomicAdd(&lcnt[r], 1u);                  \
  }
#define CT_VEC(V, X)                                                 \
  CT_ELEM((V).x, (X).x) CT_ELEM((V).y, (X).y)                        \
  CT_ELEM((V).z, (X).z) CT_ELEM((V).w, (X).w)
  for (; j + stride < nvec; j += 2 * stride) {
    vint4 va = idx4[j];
    vint4 vb = idx4[j + stride];
    vfloat4 xa = __builtin_nontemporal_load(&pv4[j]);
    vfloat4 xb = __builtin_nontemporal_load(&pv4[j + stride]);
    CT_VEC(va, xa)
    CT_VEC(vb, xb)
  }
  for (; j < nvec; j += stride) {
    vint4 va = idx4[j];
    vfloat4 xa = __builtin_nontemporal_load(&pv4[j]);
    CT_VEC(va, xa)
  }
#undef CT_VEC
#undef CT_ELEM
  __syncthreads();

  // Flush LDS counters -> packed u64 device-scope atomics (bypass L1/L2,
  // land at the coherence point; vmcnt tracks completion).
  for (int s = threadIdx.x; s < NSLOT; s += 1024) {
    u32 c0 = lcnt[4 * s + 0], c1 = lcnt[4 * s + 1];
    u32 c2 = lcnt[4 * s + 2], c3 = lcnt[4 * s + 3];
    u64 p = (u64)c0 | ((u64)c1 << 16) | ((u64)c2 << 32) | ((u64)c3 << 48);
    if (p) atomicAdd(&cnt[s], p);
  }

  // ---- last-block-done finalize, fence-free ----
  // __syncthreads drains vmcnt(0) per wave (compiler-guaranteed barrier
  // semantics), so every atomic from this block is globally complete here.
  __builtin_amdgcn_s_waitcnt(0);   // belt-and-braces: vmcnt/lgkmcnt = 0
  __syncthreads();
  if (threadIdx.x == 0) {
    u64 prev = __hip_atomic_fetch_add(&cnt[NSLOT], 1ull, __ATOMIC_RELAXED,
                                      __HIP_MEMORY_SCOPE_AGENT);
    is_last = (prev == (u64)(gridDim.x - 1));
  }
  __syncthreads();
  if (!is_last) return;

  float lsum = 0.f;
  for (int s = threadIdx.x; s < NSLOT; s += 1024) {
    u64 p = __hip_atomic_load(&cnt[s], __ATOMIC_RELAXED,
                              __HIP_MEMORY_SCOPE_AGENT);  // cache-bypassing
    float m0 = 1.0f / (float)(1u + (u32)(p & 0xFFFFu));
    float m1 = 1.0f / (float)(1u + (u32)((p >> 16) & 0xFFFFu));
    float m2 = 1.0f / (float)(1u + (u32)((p >> 32) & 0xFFFFu));
    float m3 = 1.0f / (float)(1u + (u32)((p >> 48) & 0xFFFFu));
    vfloat4 m = {m0, m1, m2, m3};
    *(vfloat4*)&out[1 + 4 * s] = m;
    lsum += m0 + m1 + m2 + m3;
  }
#pragma unroll
  for (int off = 32; off > 0; off >>= 1) lsum += __shfl_down(lsum, off, 64);
  if ((threadIdx.x & 63) == 0) wsum[threadIdx.x >> 6] = lsum;
  __syncthreads();
  if (threadIdx.x == 0) {
    float tot = 0.f;
#pragma unroll
    for (int w = 0; w < 16; ++w) tot += wsum[w];
    out[0] = tot / (float)N_POS;
  }
}

extern "C" void kernel_launch(void* const* d_in, const int* in_sizes, int n_in,
                              void* d_out, int out_size, void* d_ws, size_t ws_size,
                              hipStream_t stream) {
  const float* pv = (const float*)d_in[0];
  const int* idx = (const int*)d_in[1];
  float* out = (float*)d_out;
  float* pos = (float*)d_ws;
  u64* cnt = (u64*)((char*)d_ws + 32 * 1024);   // 2048 slots + ticket
  int nvec = in_sizes[0] / 4;   // 8,194,048

  scatter_pos_kernel<<<2048, 256, 0, stream>>>((const vint4*)idx, pv, pos,
                                               cnt, nvec);
  count_kernel<<<CNT_BLOCKS, 1024, 0, stream>>>((const vint4*)idx,
                                                (const vfloat4*)pv, pos, cnt,
                                                out, nvec);
}